// Round 9
// baseline (295.814 us; speedup 1.0000x reference)
//
#include <hip/hip_runtime.h>

#define N_EDGES 1000000
#define HID 128
#define ME 64          // edges per block; 8 waves, N split 8-ways (16 cols/wave)

typedef unsigned short ushort;
typedef unsigned int uint;
typedef __attribute__((ext_vector_type(8))) short short8;
typedef __attribute__((ext_vector_type(4))) float f32x4;

__device__ __forceinline__ float blo(uint u) { return __builtin_bit_cast(float, u << 16); }
__device__ __forceinline__ float bhi(uint u) { return __builtin_bit_cast(float, u & 0xffff0000u); }
__device__ __forceinline__ ushort f2bfbits(float f) {
  uint u = __builtin_bit_cast(uint, f);
  return (ushort)((u + 0x7fffu + ((u >> 16) & 1u)) >> 16);  // RNE
}
__device__ __forceinline__ uint cvtpk(float a, float b) {
  uint r;
  asm("v_cvt_pk_bf16_f32 %0, %1, %2" : "=v"(r) : "v"(a), "v"(b));
  return r;  // lo = bf16(a), hi = bf16(b)
}
__device__ __forceinline__ uint cvtpk_abs(float a, float b) {
  uint r;
  asm("v_cvt_pk_bf16_f32 %0, abs(%1), abs(%2)" : "=v"(r) : "v"(a), "v"(b));
  return r;
}
__device__ __forceinline__ ushort bf1(float a) { return (ushort)cvtpk(a, a); }
// XOR-swizzled element index into a [64][128] ushort LDS tile.
__device__ __forceinline__ int sidx(int r, int c) {
  return r * 128 + (c ^ ((r & 7) << 3));
}

// Pack W (row-major [K][128] f32) into B-fragment order for mfma_f32_16x16x32_bf16.
// W1p kb 0..15: k = kb*32 + (lane>>4)*8 + j (zs,zd,prod,absdiff).
// W1p kb 16..17 (tail chunk, 64 cols): c = (kb-16)*32+(lane>>4)*8+j;
//   c==0 -> k512 (dist); c in [2,34) -> k 511+c (lr_emb); else zero row.
__global__ void prep_kernel(const float* __restrict__ W1, const float* __restrict__ W2,
                            ushort* __restrict__ W1p, ushort* __restrict__ W2p) {
  const int t = blockIdx.x * blockDim.x + threadIdx.x;
  const int n1 = 18 * 8 * 64 * 8;
  if (t < n1) {
    const int j = t & 7, lane = (t >> 3) & 63, nt = (t >> 9) & 7, kb = t >> 12;
    const int col = nt * 16 + (lane & 15);
    float val = 0.f;
    if (kb < 16) {
      const int k = kb * 32 + (lane >> 4) * 8 + j;
      val = W1[k * HID + col];
    } else {
      const int c = (kb - 16) * 32 + (lane >> 4) * 8 + j;
      const int k = (c == 0) ? 512 : ((c >= 2 && c < 34) ? (511 + c) : -1);
      if (k >= 0) val = W1[k * HID + col];
    }
    W1p[t] = f2bfbits(val);
  } else {
    const int t2 = t - n1;
    if (t2 < 4 * 8 * 64 * 8) {
      const int j = t2 & 7, lane = (t2 >> 3) & 63, nt = (t2 >> 9) & 7, kb = t2 >> 12;
      const int k = kb * 32 + (lane >> 4) * 8 + j;
      const int col = nt * 16 + (lane & 15);
      W2p[t2] = f2bfbits(W2[k * HID + col]);
    }
  }
}

// R9: 8 light waves per block (16 cols each, acc[4]=16 AGPR, 8 edges gathered)
// at ME=64. (512,6) -> 3 blocks/CU x 8 waves = 24 waves/CU (+50% vs R7),
// reg cap 85 incl AGPRs, demand ~70 -> spill-free (WRITE_SIZE tripwire).
// Same proven 7-phase schedule as R7; R8's losses (2-block granularity,
// constant per-wave work) both avoided.
__global__ __launch_bounds__(512, 6)
void edge_mlp(const float* __restrict__ z, const int* __restrict__ ei,
              const float* __restrict__ ea, const float* __restrict__ lre,
              const ushort* __restrict__ W1p, const float* __restrict__ b1,
              const ushort* __restrict__ W2p, const float* __restrict__ b2,
              const float* __restrict__ W3, const float* __restrict__ b3,
              float* __restrict__ out) {
  __shared__ ushort B0[ME * 128];  // 2 buffers * 16384B = 32768B
  __shared__ ushort B1[ME * 128];

  const int tid = threadIdx.x;
  const int lane = tid & 63;
  const int w = tid >> 6;        // wave 0..7, owns output cols [16w, 16w+16)
  const int r15 = lane & 15;
  const int g = lane >> 4;
  const int half = lane >> 5;    // 0/1
  const int li = lane & 31;
  const int row0 = w * 8;        // edges this wave gathers/builds
  const int cw = w * 16;
  const int eb = blockIdx.x * ME;

  // ---- per-wave metadata: lanes 0..7 = src idx, 8..15 = dst idx,
  //      lanes 16..23 = dist(f32), 24..31 = lr_id(f32)
  int sd = 0;
  float auxv = 0.f;
  if (lane < 8)       sd = ei[eb + row0 + lane];
  else if (lane < 16) sd = ei[N_EDGES + eb + row0 + (lane - 8)];
  else if (lane < 24) auxv = ea[(eb + row0 + (lane - 16)) * 7 + 0];
  else if (lane < 32) auxv = ea[(eb + row0 + (lane - 24)) * 7 + 2];

  // ---- P0: gather zs,zd (2 edges/iter, half-wave each, same edge in same
  //      lane), write zs->B0, zd->B1; prod/absdiff f32 now -> 16 packed VGPRs.
  uint2 pr_pk[4], ad_pk[4];
#pragma unroll
  for (int t = 0; t < 4; ++t) {
    const int e = 2 * t + half;
    const int r = row0 + e;
    const int s = __shfl(sd, e);
    const int d = __shfl(sd, 8 + e);
    const float4 a = *(const float4*)(z + s * HID + 4 * li);
    const float4 b = *(const float4*)(z + d * HID + 4 * li);
    uint2 zs, zd;
    zs.x = cvtpk(a.x, a.y); zs.y = cvtpk(a.z, a.w);
    zd.x = cvtpk(b.x, b.y); zd.y = cvtpk(b.z, b.w);
    *(uint2*)&B0[sidx(r, 4 * li)] = zs;
    *(uint2*)&B1[sidx(r, 4 * li)] = zd;
    pr_pk[t].x = cvtpk(a.x * b.x, a.y * b.y);
    pr_pk[t].y = cvtpk(a.z * b.z, a.w * b.w);
    ad_pk[t].x = cvtpk_abs(a.x - b.x, a.y - b.y);
    ad_pk[t].y = cvtpk_abs(a.z - b.z, a.w - b.w);
  }
  __syncthreads();

  f32x4 acc[4];   // 4 mt x 1 nt, reused for layer 1 AND layer 2 -> 16 AGPRs
#pragma unroll
  for (int mt = 0; mt < 4; ++mt) acc[mt] = (f32x4){0.f, 0.f, 0.f, 0.f};

#define MFMA_CHUNK(BUF, NKK, KB)                                                        \
  _Pragma("unroll")                                                                     \
  for (int kk = 0; kk < (NKK); ++kk) {                                                  \
    const int kbg = (KB) + kk;                                                          \
    short8 bfr = *(const short8*)(W1p + (((kbg * 8 + w) * 64) + lane) * 8);             \
    _Pragma("unroll")                                                                   \
    for (int mt = 0; mt < 4; ++mt) {                                                    \
      short8 af = *(const short8*)&BUF[sidx(mt * 16 + r15, ((kbg) & 3) * 32 + g * 8)];  \
      acc[mt] = __builtin_amdgcn_mfma_f32_16x16x32_bf16(af, bfr, acc[mt], 0, 0, 0);     \
    }                                                                                   \
  }

  // ---- P1: MFMA zs (kb 0..3)
  __builtin_amdgcn_s_setprio(1);
  MFMA_CHUNK(B0, 4, 0)
  __builtin_amdgcn_s_setprio(0);
  __syncthreads();

  // ---- P2: prod -> B0 (pure stores from regs); MFMA zd (kb 4..7)
#pragma unroll
  for (int t = 0; t < 4; ++t)
    *(uint2*)&B0[sidx(row0 + 2 * t + half, 4 * li)] = pr_pk[t];
  __builtin_amdgcn_s_setprio(1);
  MFMA_CHUNK(B1, 4, 4)
  __builtin_amdgcn_s_setprio(0);
  __syncthreads();

  // ---- P3: absdiff -> B1 (pure stores); MFMA prod (kb 8..11)
#pragma unroll
  for (int t = 0; t < 4; ++t)
    *(uint2*)&B1[sidx(row0 + 2 * t + half, 4 * li)] = ad_pk[t];
  __builtin_amdgcn_s_setprio(1);
  MFMA_CHUNK(B0, 4, 8)
  __builtin_amdgcn_s_setprio(0);
  __syncthreads();

  // ---- P4: tail -> B0 (col0 dist, cols 2..33 lr_emb; cols 34..63 stale prod
  //      * zero weight rows = 0); MFMA absdiff (kb 12..15)
  {
    const float dv = __shfl(auxv, 16 + (lane & 7));
    if (lane < 8) B0[sidx(row0 + lane, 0)] = bf1(dv);
  }
#pragma unroll
  for (int t = 0; t < 2; ++t) {
    const int e = t * 4 + (lane >> 4);
    const int lrid = (int)__shfl(auxv, 24 + e);
    const float2 lv = *(const float2*)(lre + lrid * 32 + 2 * r15);
    *(uint*)&B0[sidx(row0 + e, 2 + 2 * r15)] = cvtpk(lv.x, lv.y);
  }
  __builtin_amdgcn_s_setprio(1);
  MFMA_CHUNK(B1, 4, 12)
  __builtin_amdgcn_s_setprio(0);
  __syncthreads();

  // ---- P5: MFMA tail (kb 16..17); h1 = relu(acc+b1) -> B1
  __builtin_amdgcn_s_setprio(1);
  MFMA_CHUNK(B0, 2, 16)
  __builtin_amdgcn_s_setprio(0);
  {
    const float b1v = b1[cw + r15];
#pragma unroll
    for (int mt = 0; mt < 4; ++mt)
#pragma unroll
      for (int j = 0; j < 4; ++j) {
        const float h = fmaxf(acc[mt][j] + b1v, 0.f);
        B1[sidx(mt * 16 + g * 4 + j, cw + r15)] = bf1(h);
      }
  }
  __syncthreads();

  // ---- P6: layer 2 (K=128) from B1 (acc reused); h2 -> B0
#pragma unroll
  for (int mt = 0; mt < 4; ++mt) acc[mt] = (f32x4){0.f, 0.f, 0.f, 0.f};
  __builtin_amdgcn_s_setprio(1);
#pragma unroll
  for (int kk = 0; kk < 4; ++kk) {
    short8 bfr = *(const short8*)(W2p + (((kk * 8 + w) * 64) + lane) * 8);
#pragma unroll
    for (int mt = 0; mt < 4; ++mt) {
      short8 af = *(const short8*)&B1[sidx(mt * 16 + r15, kk * 32 + g * 8)];
      acc[mt] = __builtin_amdgcn_mfma_f32_16x16x32_bf16(af, bfr, acc[mt], 0, 0, 0);
    }
  }
  __builtin_amdgcn_s_setprio(0);
  {
    const float b2v = b2[cw + r15];
#pragma unroll
    for (int mt = 0; mt < 4; ++mt)
#pragma unroll
      for (int j = 0; j < 4; ++j) {
        const float h = fmaxf(acc[mt][j] + b2v, 0.f);
        B0[sidx(mt * 16 + g * 4 + j, cw + r15)] = bf1(h);
      }
  }
  __syncthreads();

  // ---- P7: layer 3 from B0: thread -> row w*8+(lane>>3), cols (lane&7)*16..+15
  {
    const int row = w * 8 + (lane >> 3);
    const int cg = lane & 7;
    float sum = 0.f;
#pragma unroll
    for (int i = 0; i < 2; ++i) {
      const int c0 = cg * 16 + i * 8;
      const uint4 hv = *(const uint4*)&B0[sidx(row, c0)];
#pragma unroll
      for (int p = 0; p < 4; ++p) {
        const uint u = ((const uint*)&hv)[p];
        const float2 wv = *(const float2*)(W3 + c0 + 2 * p);
        sum += blo(u) * wv.x + bhi(u) * wv.y;
      }
    }
    sum += __shfl_xor(sum, 1);
    sum += __shfl_xor(sum, 2);
    sum += __shfl_xor(sum, 4);
    if (cg == 0) out[eb + row] = sum + b3[0];
  }
}

extern "C" void kernel_launch(void* const* d_in, const int* in_sizes, int n_in,
                              void* d_out, int out_size, void* d_ws, size_t ws_size,
                              hipStream_t stream) {
  const float* z   = (const float*)d_in[0];
  const int*   ei  = (const int*)d_in[1];
  const float* ea  = (const float*)d_in[2];
  const float* lre = (const float*)d_in[3];
  const float* W1  = (const float*)d_in[4];
  const float* b1  = (const float*)d_in[5];
  const float* W2  = (const float*)d_in[6];
  const float* b2  = (const float*)d_in[7];
  const float* W3  = (const float*)d_in[8];
  const float* b3  = (const float*)d_in[9];
  float* out = (float*)d_out;

  ushort* W1p = (ushort*)d_ws;              // 18*8*64*8 = 73728 bf16
  ushort* W2p = W1p + 18 * 8 * 64 * 8;      // 4*8*64*8  = 16384 bf16

  prep_kernel<<<352, 256, 0, stream>>>(W1, W2, W1p, W2p);
  edge_mlp<<<N_EDGES / ME, 512, 0, stream>>>(z, ei, ea, lre, W1p, b1, W2p, b2, W3, b3, out);
}

// Round 10
// 260.541 us; speedup vs baseline: 1.1354x; 1.1354x over previous
//
#include <hip/hip_runtime.h>

#define N_EDGES 1000000
#define HID 128
#define ME 64          // edges per block (col-split: each wave owns one 32-col n-tile)
#define NK1 35         // layer-1 K-steps of 16: 32 (zs,zd,pr,ad) + 3 tail (48 cols)

typedef unsigned short ushort;
typedef unsigned int uint;
typedef __attribute__((ext_vector_type(8))) short short8;
typedef __attribute__((ext_vector_type(16))) float f32x16;

__device__ __forceinline__ float blo(uint u) { return __builtin_bit_cast(float, u << 16); }
__device__ __forceinline__ float bhi(uint u) { return __builtin_bit_cast(float, u & 0xffff0000u); }
__device__ __forceinline__ ushort f2bfbits(float f) {
  uint u = __builtin_bit_cast(uint, f);
  return (ushort)((u + 0x7fffu + ((u >> 16) & 1u)) >> 16);  // RNE
}
__device__ __forceinline__ uint cvtpk(float a, float b) {
  uint r;
  asm("v_cvt_pk_bf16_f32 %0, %1, %2" : "=v"(r) : "v"(a), "v"(b));
  return r;  // lo = bf16(a), hi = bf16(b)
}
__device__ __forceinline__ uint cvtpk_abs(float a, float b) {
  uint r;
  asm("v_cvt_pk_bf16_f32 %0, abs(%1), abs(%2)" : "=v"(r) : "v"(a), "v"(b));
  return r;
}
__device__ __forceinline__ ushort bf1(float a) { return (ushort)cvtpk(a, a); }
// XOR-swizzled element index into a [64][128] ushort LDS tile.
__device__ __forceinline__ int sidx(int r, int c) {
  return r * 128 + (c ^ ((r & 7) << 3));
}

// Pack W (row-major [K][128] f32) into B-fragment order for mfma_f32_32x32x16_bf16:
// B-frag: col = nt*32 + (lane&31), k = ks*16 + (lane>>5)*8 + j.
// W1p ks 0..31: k as-is (zs,zd,prod,absdiff = K 0..511).
// W1p ks 32..34 (tail, 48 cols): c = (ks-32)*16+(lane>>5)*8+j;
//   c==0 -> k512 (dist); c in [2,34) -> k 511+c (lr_emb); else zero row.
__global__ void prep_kernel(const float* __restrict__ W1, const float* __restrict__ W2,
                            ushort* __restrict__ W1p, ushort* __restrict__ W2p) {
  const int t = blockIdx.x * blockDim.x + threadIdx.x;
  const int n1 = NK1 << 11;  // 35*4*64*8 = 71680
  if (t < n1) {
    const int j = t & 7, lane = (t >> 3) & 63, nt = (t >> 9) & 3, ks = t >> 11;
    const int col = nt * 32 + (lane & 31);
    const int kk = (lane >> 5) * 8 + j;
    float val = 0.f;
    if (ks < 32) {
      val = W1[(ks * 16 + kk) * HID + col];
    } else {
      const int c = (ks - 32) * 16 + kk;
      const int k = (c == 0) ? 512 : ((c >= 2 && c < 34) ? (511 + c) : -1);
      if (k >= 0) val = W1[k * HID + col];
    }
    W1p[t] = f2bfbits(val);
  } else {
    const int t2 = t - n1;
    if (t2 < (8 << 11)) {
      const int j = t2 & 7, lane = (t2 >> 3) & 63, nt = (t2 >> 9) & 3, ks = t2 >> 11;
      W2p[t2] = f2bfbits(W2[(ks * 16 + (lane >> 5) * 8 + j) * HID + nt * 32 + (lane & 31)]);
    }
  }
}

// R10: R7 skeleton (4 waves, 2 buffers, 7 phases, 4 blocks/CU) with 32x32x16
// MFMA: 17% less matrix-pipe time per FLOP (2382 vs 2075 TF), half the MFMA
// instructions, tail padding 64->48 cols. Reg cap (256,4)=128 incl AGPRs:
// acc 32 AGPR + pr/ad 32 VGPR + transients -> spill-free (WRITE_SIZE tripwire).
__global__ __launch_bounds__(256, 4)
void edge_mlp(const float* __restrict__ z, const int* __restrict__ ei,
              const float* __restrict__ ea, const float* __restrict__ lre,
              const ushort* __restrict__ W1p, const float* __restrict__ b1,
              const ushort* __restrict__ W2p, const float* __restrict__ b2,
              const float* __restrict__ W3, const float* __restrict__ b3,
              float* __restrict__ out) {
  __shared__ ushort B0[ME * 128];  // 2 buffers * 16384B = 32768B
  __shared__ ushort B1[ME * 128];

  const int tid = threadIdx.x;
  const int lane = tid & 63;
  const int w = tid >> 6;        // wave 0..3, owns output cols [32w, 32w+32)
  const int r15 = lane & 15;
  const int g = lane >> 4;
  const int half = lane >> 5;    // 0/1
  const int li = lane & 31;
  const int hi = lane >> 5;
  const int row0 = w * 16;       // edges this wave gathers/builds
  const int cw = w * 32;
  const int eb = blockIdx.x * ME;

  // ---- per-wave metadata: lanes 0..15 = src idx, 16..31 = dst idx,
  //      lanes 32..47 = dist(f32), 48..63 = lr_id(f32)
  int sd = 0;
  float auxv = 0.f;
  if (lane < 16)      sd = ei[eb + row0 + lane];
  else if (lane < 32) sd = ei[N_EDGES + eb + row0 + (lane - 16)];
  else if (lane < 48) auxv = ea[(eb + row0 + (lane - 32)) * 7 + 0];
  else                auxv = ea[(eb + row0 + (lane - 48)) * 7 + 2];

  // ---- P0: gather zs,zd (same edge in same lane), write zs->B0, zd->B1;
  //      prod/absdiff computed in f32 NOW, held packed in 32 VGPRs.
  uint2 pr_pk[8], ad_pk[8];
#pragma unroll
  for (int t = 0; t < 8; ++t) {
    const int e = 2 * t + half;
    const int r = row0 + e;
    const int s = __shfl(sd, e);
    const int d = __shfl(sd, 16 + e);
    const float4 a = *(const float4*)(z + s * HID + 4 * li);
    const float4 b = *(const float4*)(z + d * HID + 4 * li);
    uint2 zs, zd;
    zs.x = cvtpk(a.x, a.y); zs.y = cvtpk(a.z, a.w);
    zd.x = cvtpk(b.x, b.y); zd.y = cvtpk(b.z, b.w);
    *(uint2*)&B0[sidx(r, 4 * li)] = zs;
    *(uint2*)&B1[sidx(r, 4 * li)] = zd;
    pr_pk[t].x = cvtpk(a.x * b.x, a.y * b.y);
    pr_pk[t].y = cvtpk(a.z * b.z, a.w * b.w);
    ad_pk[t].x = cvtpk_abs(a.x - b.x, a.y - b.y);
    ad_pk[t].y = cvtpk_abs(a.z - b.z, a.w - b.w);
  }
  __syncthreads();

  f32x16 acc[2];   // 2 m-tiles x 1 n-tile, reused for layer 1 AND 2 -> 32 AGPRs
#pragma unroll
  for (int mt = 0; mt < 2; ++mt)
#pragma unroll
    for (int rg = 0; rg < 16; ++rg) acc[mt][rg] = 0.f;

  // One K=16 step: A-frag row = mt*32+(lane&31), k-col = (ks&7)*16 + hi*8;
  // B-frag (W) from WP at n-tile w.
#define MFMA_KS(BUF, WP, NKS, KS0)                                                      \
  _Pragma("unroll")                                                                     \
  for (int ks = 0; ks < (NKS); ++ks) {                                                  \
    const int ksg = (KS0) + ks;                                                         \
    short8 bfr = *(const short8*)((WP) + (((ksg * 4 + w) * 64) + lane) * 8);            \
    _Pragma("unroll")                                                                   \
    for (int mt = 0; mt < 2; ++mt) {                                                    \
      short8 af = *(const short8*)&BUF[sidx(mt * 32 + li, ((ksg & 7) * 16) + hi * 8)];  \
      acc[mt] = __builtin_amdgcn_mfma_f32_32x32x16_bf16(af, bfr, acc[mt], 0, 0, 0);     \
    }                                                                                   \
  }

  // ---- P1: MFMA zs (ks 0..7)
  __builtin_amdgcn_s_setprio(1);
  MFMA_KS(B0, W1p, 8, 0)
  __builtin_amdgcn_s_setprio(0);
  __syncthreads();

  // ---- P2: prod -> B0 (pure stores from regs); MFMA zd (ks 8..15)
#pragma unroll
  for (int t = 0; t < 8; ++t)
    *(uint2*)&B0[sidx(row0 + 2 * t + half, 4 * li)] = pr_pk[t];
  __builtin_amdgcn_s_setprio(1);
  MFMA_KS(B1, W1p, 8, 8)
  __builtin_amdgcn_s_setprio(0);
  __syncthreads();

  // ---- P3: absdiff -> B1 (pure stores); MFMA prod (ks 16..23)
#pragma unroll
  for (int t = 0; t < 8; ++t)
    *(uint2*)&B1[sidx(row0 + 2 * t + half, 4 * li)] = ad_pk[t];
  __builtin_amdgcn_s_setprio(1);
  MFMA_KS(B0, W1p, 8, 16)
  __builtin_amdgcn_s_setprio(0);
  __syncthreads();

  // ---- P4: tail -> B0 (col0 dist, cols 2..33 lr_emb; cols 34..47 stale prod
  //      * zero weight rows = 0; cols 48+ never read); MFMA absdiff (ks 24..31)
  {
    const float dv = __shfl(auxv, 32 + r15);
    if (lane < 16) B0[sidx(row0 + lane, 0)] = bf1(dv);
  }
#pragma unroll
  for (int t = 0; t < 4; ++t) {
    const int e = 4 * t + g;
    const int lrid = (int)__shfl(auxv, 48 + e);
    const float2 lv = *(const float2*)(lre + lrid * 32 + 2 * r15);
    *(uint*)&B0[sidx(row0 + e, 2 + 2 * r15)] = cvtpk(lv.x, lv.y);
  }
  __builtin_amdgcn_s_setprio(1);
  MFMA_KS(B1, W1p, 8, 24)
  __builtin_amdgcn_s_setprio(0);
  __syncthreads();

  // ---- P5: MFMA tail (ks 32..34); h1 = relu(acc+b1) -> B1
  __builtin_amdgcn_s_setprio(1);
  MFMA_KS(B0, W1p, 3, 32)
  __builtin_amdgcn_s_setprio(0);
  {
    const float b1v = b1[cw + li];
#pragma unroll
    for (int mt = 0; mt < 2; ++mt)
#pragma unroll
      for (int rg = 0; rg < 16; ++rg) {
        const int row = mt * 32 + (rg & 3) + 8 * (rg >> 2) + 4 * hi;
        const float h = fmaxf(acc[mt][rg] + b1v, 0.f);
        B1[sidx(row, cw + li)] = bf1(h);
      }
  }
  __syncthreads();

  // ---- P6: layer 2 (K=128, ks 0..7) from B1 (acc reused); h2 -> B0
#pragma unroll
  for (int mt = 0; mt < 2; ++mt)
#pragma unroll
    for (int rg = 0; rg < 16; ++rg) acc[mt][rg] = 0.f;
  __builtin_amdgcn_s_setprio(1);
  MFMA_KS(B1, W2p, 8, 0)
  __builtin_amdgcn_s_setprio(0);
  {
    const float b2v = b2[cw + li];
#pragma unroll
    for (int mt = 0; mt < 2; ++mt)
#pragma unroll
      for (int rg = 0; rg < 16; ++rg) {
        const int row = mt * 32 + (rg & 3) + 8 * (rg >> 2) + 4 * hi;
        const float h = fmaxf(acc[mt][rg] + b2v, 0.f);
        B0[sidx(row, cw + li)] = bf1(h);
      }
  }
  __syncthreads();

  // ---- P7: layer 3 from B0: lane -> row w*16+r15, cols g*32..g*32+31
  {
    const int rr = w * 16 + r15;
    float sum = 0.f;
#pragma unroll
    for (int i = 0; i < 4; ++i) {
      const int c0 = g * 32 + i * 8;
      const uint4 hv = *(const uint4*)&B0[sidx(rr, c0)];
#pragma unroll
      for (int p = 0; p < 4; ++p) {
        const uint u = ((const uint*)&hv)[p];
        const float2 wv = *(const float2*)(W3 + c0 + 2 * p);
        sum += blo(u) * wv.x + bhi(u) * wv.y;
      }
    }
    sum += __shfl_xor(sum, 16);
    sum += __shfl_xor(sum, 32);
    if (lane < 16) out[eb + rr] = sum + b3[0];
  }
}

extern "C" void kernel_launch(void* const* d_in, const int* in_sizes, int n_in,
                              void* d_out, int out_size, void* d_ws, size_t ws_size,
                              hipStream_t stream) {
  const float* z   = (const float*)d_in[0];
  const int*   ei  = (const int*)d_in[1];
  const float* ea  = (const float*)d_in[2];
  const float* lre = (const float*)d_in[3];
  const float* W1  = (const float*)d_in[4];
  const float* b1  = (const float*)d_in[5];
  const float* W2  = (const float*)d_in[6];
  const float* b2  = (const float*)d_in[7];
  const float* W3  = (const float*)d_in[8];
  const float* b3  = (const float*)d_in[9];
  float* out = (float*)d_out;

  ushort* W1p = (ushort*)d_ws;              // 35*4*64*8 = 71680 bf16
  ushort* W2p = W1p + (NK1 << 11);          // 8*4*64*8  = 16384 bf16

  prep_kernel<<<344, 256, 0, stream>>>(W1, W2, W1p, W2p);
  edge_mlp<<<N_EDGES / ME, 256, 0, stream>>>(z, ei, ea, lre, W1p, b1, W2p, b2, W3, b3, out);
}